// Round 8
// baseline (173.226 us; speedup 1.0000x reference)
//
#include <hip/hip_runtime.h>
#include <hip/hip_bf16.h>

#define BB 16
#define NN 512
#define NH 8
#define DD 64
#define CK 64        // keys per chunk
#define NCH 8        // NN / CK
#define TL 4         // 16-key tiles per chunk
// main kernel
#define MWAVES 8
#define MQBLK 128    // q rows per block (8 waves x 16)
// fallback kernel (round-1)
#define QBLK 64
#define WAVES 4
#define KBLK 128
#define NCHUNK 4
#define NT 32
#define TPC 8

#define C_QK   23.083120654223414f   // 16 * log2(e)
#define C_GEO  11.541560327111707f   // 8 * log2(e)

typedef __attribute__((ext_vector_type(8))) short bf16x8;
typedef __attribute__((ext_vector_type(4))) float f32x4;

__device__ __forceinline__ unsigned short f2bf(float f) {
    unsigned int u = __float_as_uint(f);
    u += 0x7fffu + ((u >> 16) & 1u);     // round-to-nearest-even
    return (unsigned short)(u >> 16);
}
__device__ __forceinline__ float bf2f(unsigned short h) {
    return __uint_as_float(((unsigned int)h) << 16);
}
// packed f32x2 -> bf16x2 (RNE), one instruction
__device__ __forceinline__ unsigned int cvtpk(float a, float b) {
    unsigned int r;
    asm("v_cvt_pk_bf16_f32 %0, %1, %2" : "=v"(r) : "v"(a), "v"(b));
    return r;
}
// 2^x, single v_exp_f32 (no libm slow path)
__device__ __forceinline__ float exp2fast(float x) {
    float r;
    asm("v_exp_f32 %0, %1" : "=v"(r) : "v"(x));
    return r;
}
// async global->LDS, 16B per lane; LDS dest = wave-uniform base + lane*16
__device__ __forceinline__ void gload16(const void* gsrc, void* lds) {
    __builtin_amdgcn_global_load_lds(
        (const __attribute__((address_space(1))) unsigned int*)gsrc,
        (__attribute__((address_space(3))) unsigned int*)lds, 16, 0, 0);
}

// ---------------- prep ----------------
// K image rows PERMUTED so QK^T D-layout slot j=16tl+4g+r holds physical key
// p = 32*(tl>>1) + 8g + 4*(tl&1) + r  ->  each lane's P row is PV-B-frag-ready.
// j(kl) = 16*(((kl&7)>>2) + 2*(kl>>5)) + 4*((kl>>3)&3) + (kl&3)
// V^T image stays physical-key-ordered. k2G stores -8*log2(e)*||k||^2.
__global__ __launch_bounds__(256) void geo_prep(
    const float* __restrict__ K, const float* __restrict__ V,
    unsigned short* __restrict__ KhiG, unsigned short* __restrict__ KloG,
    unsigned short* __restrict__ VtG, float* __restrict__ k2G)
{
    const int c2 = blockIdx.x;   // 0..7 key chunk
    const int h  = blockIdx.y;
    const int b  = blockIdx.z;
    const int bh = b*NH + h;
    const int tid = threadIdx.x;
    const int lane16 = tid & 15;
    const int grp    = tid >> 4;   // 0..15

    __shared__ unsigned short Vl[DD*66];

    const size_t kbase = (size_t)bh*(NN*DD) + (size_t)c2*(CK*DD);
    #pragma unroll
    for (int kk = 0; kk < 4; ++kk) {
        const int kl = kk*16 + grp;
        const float* krow = K + ((size_t)(((b*NN + c2*CK + kl)*NH) + h))*DD + lane16*4;
        const float* vrow = V + ((size_t)(((b*NN + c2*CK + kl)*NH) + h))*DD + lane16*4;
        float4 kf = *(const float4*)krow;
        float4 vf = *(const float4*)vrow;
        float fb[4] = {kf.x, kf.y, kf.z, kf.w};
        float vb[4] = {vf.x, vf.y, vf.z, vf.w};
        unsigned short hu[4], lu[4];
        float k2s = 0.f;
        #pragma unroll
        for (int e = 0; e < 4; ++e) {
            float f = fb[e];
            k2s += f*f;
            hu[e] = f2bf(f);
            lu[e] = f2bf(f - bf2f(hu[e]));
            Vl[(lane16*4 + e)*66 + kl] = f2bf(vb[e]);
        }
        k2s += __shfl_xor(k2s, 1);
        k2s += __shfl_xor(k2s, 2);
        k2s += __shfl_xor(k2s, 4);
        k2s += __shfl_xor(k2s, 8);
        if (lane16 == 0) k2G[bh*NN + c2*CK + kl] = -C_GEO * k2s;   // log2-domain pre-scale
        const int j = 16*(((kl & 7) >> 2) + 2*(kl >> 5)) + 4*((kl >> 3) & 3) + (kl & 3);
        const int pos = (j*DD + lane16*4) ^ ((j & 7) << 3);
        *(uint2*)&KhiG[kbase + pos] = make_uint2((unsigned)hu[0] | ((unsigned)hu[1] << 16),
                                                 (unsigned)hu[2] | ((unsigned)hu[3] << 16));
        *(uint2*)&KloG[kbase + pos] = make_uint2((unsigned)lu[0] | ((unsigned)lu[1] << 16),
                                                 (unsigned)lu[2] | ((unsigned)lu[3] << 16));
    }
    __syncthreads();
    const size_t vbase = ((size_t)bh*NCH + c2)*(DD*CK);
    #pragma unroll
    for (int i = 0; i < 4; ++i) {
        const int gi = tid + 256*i;
        const int d   = gi >> 4;
        const int kl4 = (gi & 15) * 4;
        unsigned short e0 = Vl[d*66 + kl4+0];
        unsigned short e1 = Vl[d*66 + kl4+1];
        unsigned short e2 = Vl[d*66 + kl4+2];
        unsigned short e3 = Vl[d*66 + kl4+3];
        const int pos = (d*CK + kl4) ^ ((d & 7) << 3);
        *(uint2*)&VtG[vbase + pos] = make_uint2((unsigned)e0 | ((unsigned)e1 << 16),
                                                (unsigned)e2 | ((unsigned)e3 << 16));
    }
}

// ---------------- main: swapped QK^T, permuted keys, P in-register,
//                  geo prefetched one chunk ahead in NAMED registers ----------------
__global__ __launch_bounds__(512, 4) void geo_attn_main(
    const float* __restrict__ Q, const float* __restrict__ GEO,
    const unsigned short* __restrict__ KhiG, const unsigned short* __restrict__ KloG,
    const unsigned short* __restrict__ VtG, const float* __restrict__ k2G,
    float* __restrict__ OUT)
{
    // XCD-bijective swizzle (512 % 8 == 0): b-major grouping per XCD
    const int bid  = blockIdx.x;
    const int tile = (bid & 7) * 64 + (bid >> 3);
    const int qt = tile & 3;
    const int h  = (tile >> 2) & 7;
    const int b  = tile >> 5;
    const int bh = b*NH + h;
    const int tid = threadIdx.x;
    const int w    = tid >> 6;
    const int lane = tid & 63;
    const int g = lane >> 4;
    const int c = lane & 15;

    __shared__ unsigned short Khi[2][CK*DD];     // 2 x 8KB
    __shared__ unsigned short Klo[2][CK*DD];     // 2 x 8KB
    __shared__ unsigned short vT [2][CK*DD];     // 2 x 8KB
    __shared__ float k2n[NN];                    // 2KB, holds -8*log2e*k2

    k2n[tid] = k2G[(size_t)bh*NN + tid];         // 512 threads == NN

    const int qb = qt*MQBLK + w*16;

    // Q fragments (hi/lo split); q^2 dropped (softmax shift-invariant per row)
    bf16x8 qhi[2], qlo[2];
    {
        const float* qrow = Q + ((size_t)((b*NN + qb + c)*NH + h))*DD;
        #pragma unroll
        for (int dc = 0; dc < 2; ++dc) {
            float buf[8];
            *(float4*)&buf[0] = *(const float4*)(qrow + dc*32 + g*8);
            *(float4*)&buf[4] = *(const float4*)(qrow + dc*32 + g*8 + 4);
            #pragma unroll
            for (int i = 0; i < 8; ++i) {
                float f = buf[i];
                unsigned short hu = f2bf(f);
                qhi[dc][i] = (short)hu;
                qlo[dc][i] = (short)f2bf(f - bf2f(hu));
            }
        }
    }

    f32x4 oacc[4];
    #pragma unroll
    for (int cb = 0; cb < 4; ++cb) { oacc[cb][0]=0.f; oacc[cb][1]=0.f; oacc[cb][2]=0.f; oacc[cb][3]=0.f; }
    float m_run = -3e38f;
    float l_run = 0.f;   // PARTIAL (this replica's 16 keys); reduced once in epilogue

    const char* gKhiB = (const char*)KhiG + (size_t)bh*(NN*DD*2);
    const char* gKloB = (const char*)KloG + (size_t)bh*(NN*DD*2);
    const char* gVtB  = (const char*)VtG  + (size_t)bh*(NN*DD*2);
    const float* geoR = GEO + (size_t)b*NN*NN + (size_t)(qb + c)*NN;   // this lane's q-row
    const int stoff = w*1024 + (lane<<4);

// stage chunk CH2 into buffer BUF (3 async DMAs per wave)
#define STAGE(BUF, CH2) {                                                        \
    const size_t srcoff = (size_t)(CH2)*(CK*DD*2) + stoff;                       \
    gload16(gKhiB + srcoff, (char*)&Khi[BUF][0] + w*1024);                       \
    gload16(gKloB + srcoff, (char*)&Klo[BUF][0] + w*1024);                       \
    gload16(gVtB  + srcoff, (char*)&vT [BUF][0] + w*1024);                       \
}
// geo for chunk CH into 4 named float4s (permuted-slot layout, 4-contiguous)
#define LOAD_GEO(CH, D0, D1, D2, D3) {                                           \
    const float* gb_ = geoR + (CH)*CK + 8*g;                                     \
    D0 = *(const float4*)(gb_);                                                  \
    D1 = *(const float4*)(gb_ + 4);                                              \
    D2 = *(const float4*)(gb_ + 32);                                             \
    D3 = *(const float4*)(gb_ + 36);                                             \
}
// full chunk compute: QK^T (split bf16) -> logits -> online softmax -> PV
#define COMPUTE(CH, CUR, G0, G1, G2, G3) {                                       \
    f32x4 sacc[TL];                                                              \
    _Pragma("unroll")                                                            \
    for (int tl = 0; tl < TL; ++tl) { sacc[tl][0]=0.f; sacc[tl][1]=0.f; sacc[tl][2]=0.f; sacc[tl][3]=0.f; } \
    __builtin_amdgcn_s_setprio(1);                                               \
    _Pragma("unroll")                                                            \
    for (int tl = 0; tl < TL; ++tl) {                                            \
        _Pragma("unroll")                                                        \
        for (int dc = 0; dc < 2; ++dc) {                                         \
            const int idx = ((tl*16 + c)*DD + dc*32 + g*8) ^ ((c & 7) << 3);     \
            bf16x8 kh = *(const bf16x8*)&Khi[CUR][idx];                          \
            bf16x8 kl = *(const bf16x8*)&Klo[CUR][idx];                          \
            sacc[tl] = __builtin_amdgcn_mfma_f32_16x16x32_bf16(kh, qhi[dc], sacc[tl], 0,0,0); \
            sacc[tl] = __builtin_amdgcn_mfma_f32_16x16x32_bf16(kh, qlo[dc], sacc[tl], 0,0,0); \
            sacc[tl] = __builtin_amdgcn_mfma_f32_16x16x32_bf16(kl, qhi[dc], sacc[tl], 0,0,0); \
        }                                                                        \
    }                                                                            \
    __builtin_amdgcn_s_setprio(0);                                               \
    const float4 kn0 = *(const float4*)&k2n[(CH)*CK + 8*g];                      \
    const float4 kn1 = *(const float4*)&k2n[(CH)*CK + 8*g + 4];                  \
    const float4 kn2 = *(const float4*)&k2n[(CH)*CK + 8*g + 32];                 \
    const float4 kn3 = *(const float4*)&k2n[(CH)*CK + 8*g + 36];                 \
    float p[16];                                                                 \
    p[0]  = fmaf(C_QK, sacc[0][0], fmaf(C_GEO, G0.x, kn0.x));                    \
    p[1]  = fmaf(C_QK, sacc[0][1], fmaf(C_GEO, G0.y, kn0.y));                    \
    p[2]  = fmaf(C_QK, sacc[0][2], fmaf(C_GEO, G0.z, kn0.z));                    \
    p[3]  = fmaf(C_QK, sacc[0][3], fmaf(C_GEO, G0.w, kn0.w));                    \
    p[4]  = fmaf(C_QK, sacc[1][0], fmaf(C_GEO, G1.x, kn1.x));                    \
    p[5]  = fmaf(C_QK, sacc[1][1], fmaf(C_GEO, G1.y, kn1.y));                    \
    p[6]  = fmaf(C_QK, sacc[1][2], fmaf(C_GEO, G1.z, kn1.z));                    \
    p[7]  = fmaf(C_QK, sacc[1][3], fmaf(C_GEO, G1.w, kn1.w));                    \
    p[8]  = fmaf(C_QK, sacc[2][0], fmaf(C_GEO, G2.x, kn2.x));                    \
    p[9]  = fmaf(C_QK, sacc[2][1], fmaf(C_GEO, G2.y, kn2.y));                    \
    p[10] = fmaf(C_QK, sacc[2][2], fmaf(C_GEO, G2.z, kn2.z));                    \
    p[11] = fmaf(C_QK, sacc[2][3], fmaf(C_GEO, G2.w, kn2.w));                    \
    p[12] = fmaf(C_QK, sacc[3][0], fmaf(C_GEO, G3.x, kn3.x));                    \
    p[13] = fmaf(C_QK, sacc[3][1], fmaf(C_GEO, G3.y, kn3.y));                    \
    p[14] = fmaf(C_QK, sacc[3][2], fmaf(C_GEO, G3.z, kn3.z));                    \
    p[15] = fmaf(C_QK, sacc[3][3], fmaf(C_GEO, G3.w, kn3.w));                    \
    float mx[8];                                                                 \
    _Pragma("unroll")                                                            \
    for (int i = 0; i < 8; ++i) mx[i] = fmaxf(p[i], p[i+8]);                     \
    _Pragma("unroll")                                                            \
    for (int i = 0; i < 4; ++i) mx[i] = fmaxf(mx[i], mx[i+4]);                   \
    mx[0] = fmaxf(mx[0], mx[2]); mx[1] = fmaxf(mx[1], mx[3]);                    \
    float cmax = fmaxf(mx[0], mx[1]);                                            \
    cmax = fmaxf(cmax, __shfl_xor(cmax, 16));                                    \
    cmax = fmaxf(cmax, __shfl_xor(cmax, 32));                                    \
    const float mnew = fmaxf(m_run, cmax);                                       \
    const float fac = exp2fast(m_run - mnew);                                    \
    m_run = mnew;                                                                \
    _Pragma("unroll")                                                            \
    for (int i = 0; i < 16; ++i) p[i] = exp2fast(p[i] - mnew);                   \
    float sx[8];                                                                 \
    _Pragma("unroll")                                                            \
    for (int i = 0; i < 8; ++i) sx[i] = p[i] + p[i+8];                           \
    _Pragma("unroll")                                                            \
    for (int i = 0; i < 4; ++i) sx[i] = sx[i] + sx[i+4];                         \
    const float cs = (sx[0] + sx[2]) + (sx[1] + sx[3]);                          \
    l_run = fmaf(l_run, fac, cs);  /* partial sum; fac is replica-uniform */     \
    union { unsigned int u[4]; bf16x8 v; } pf0, pf1;                             \
    pf0.u[0] = cvtpk(p[0], p[1]);  pf0.u[1] = cvtpk(p[2],  p[3]);                \
    pf0.u[2] = cvtpk(p[4], p[5]);  pf0.u[3] = cvtpk(p[6],  p[7]);                \
    pf1.u[0] = cvtpk(p[8], p[9]);  pf1.u[1] = cvtpk(p[10], p[11]);               \
    pf1.u[2] = cvtpk(p[12],p[13]); pf1.u[3] = cvtpk(p[14], p[15]);               \
    _Pragma("unroll")                                                            \
    for (int cb = 0; cb < 4; ++cb) {                                             \
        oacc[cb][0] *= fac; oacc[cb][1] *= fac; oacc[cb][2] *= fac; oacc[cb][3] *= fac; \
    }                                                                            \
    __builtin_amdgcn_s_setprio(1);                                               \
    _Pragma("unroll")                                                            \
    for (int kc = 0; kc < 2; ++kc) {                                             \
        bf16x8 pf = kc ? pf1.v : pf0.v;                                          \
        _Pragma("unroll")                                                        \
        for (int cb = 0; cb < 4; ++cb) {                                         \
            const int d = cb*16 + c;                                             \
            bf16x8 vfr = *(const bf16x8*)&vT[CUR][(d*CK + kc*32 + g*8) ^ ((d & 7) << 3)]; \
            oacc[cb] = __builtin_amdgcn_mfma_f32_16x16x32_bf16(vfr, pf, oacc[cb], 0,0,0); \
        }                                                                        \
    }                                                                            \
    __builtin_amdgcn_s_setprio(0);                                               \
}

    float4 gA0, gA1, gA2, gA3;   // geo for current even chunk
    float4 gB0, gB1, gB2, gB3;   // geo for next odd chunk

    // prologue: stage chunk 0, preload its geo
    STAGE(0, 0);
    LOAD_GEO(0, gA0, gA1, gA2, gA3);
    __syncthreads();   // chunk 0 staged + k2n visible

    #pragma unroll
    for (int cc = 0; cc < 4; ++cc) {
        const int ch0 = cc*2;
        // even chunk (buffer 0, geo gA): prefetch odd chunk's K/V + geo
        STAGE(1, ch0 + 1);
        LOAD_GEO(ch0 + 1, gB0, gB1, gB2, gB3);
        COMPUTE(ch0, 0, gA0, gA1, gA2, gA3);
        __syncthreads();
        // odd chunk (buffer 1, geo gB): prefetch next even chunk's K/V + geo
        if (cc < 3) {
            STAGE(0, ch0 + 2);
            LOAD_GEO(ch0 + 2, gA0, gA1, gA2, gA3);
        }
        COMPUTE(ch0 + 1, 1, gB0, gB1, gB2, gB3);
        __syncthreads();
    }

    // epilogue: fold replica partial sums (deferred from the loop), then store
    l_run += __shfl_xor(l_run, 16);
    l_run += __shfl_xor(l_run, 32);
    const float inv = 1.f / l_run;
    float* orow = OUT + ((size_t)((b*NN + qb + c)*NH + h))*DD + 4*g;
    #pragma unroll
    for (int cb = 0; cb < 4; ++cb) {
        float4 ov;
        ov.x = oacc[cb][0] * inv;
        ov.y = oacc[cb][1] * inv;
        ov.z = oacc[cb][2] * inv;
        ov.w = oacc[cb][3] * inv;
        *(float4*)(orow + cb*16) = ov;
    }
#undef STAGE
#undef LOAD_GEO
#undef COMPUTE
}

// ---------------- fallback (round-1 kernel, used if ws too small) ----------------
__global__ __launch_bounds__(256, 2) void geo_attn_fallback(
    const float* __restrict__ Q, const float* __restrict__ K,
    const float* __restrict__ V, const float* __restrict__ GEO,
    float* __restrict__ OUT)
{
    const int qt  = blockIdx.x;
    const int h   = blockIdx.y;
    const int b   = blockIdx.z;
    const int tid = threadIdx.x;
    const int w    = tid >> 6;
    const int lane = tid & 63;
    const int g = lane >> 4;
    const int c = lane & 15;

    __shared__ unsigned short smemA[16384];
    __shared__ float k2p[2][NN];
    __shared__ float rowinvF[WAVES][16];

    unsigned short* KhiF = smemA;
    unsigned short* KloF = smemA + KBLK*DD;
    unsigned short* vTF  = smemA;
    unsigned short* PldF = smemA + DD*KBLK + w*16*KBLK;

    const int qb = qt*QBLK + w*16;

    bf16x8 qhi[2], qlo[2];
    float q2v = 0.f;
    {
        const float* qrow = Q + ((size_t)((b*NN + qb + c)*NH + h))*DD;
        #pragma unroll
        for (int dc = 0; dc < 2; ++dc) {
            float buf[8];
            *(float4*)&buf[0] = *(const float4*)(qrow + dc*32 + g*8);
            *(float4*)&buf[4] = *(const float4*)(qrow + dc*32 + g*8 + 4);
            #pragma unroll
            for (int i = 0; i < 8; ++i) {
                float f = buf[i];
                q2v += f*f;
                unsigned short hu = f2bf(f);
                qhi[dc][i] = (short)hu;
                qlo[dc][i] = (short)f2bf(f - bf2f(hu));
            }
        }
    }
    q2v += __shfl_xor(q2v, 16);
    q2v += __shfl_xor(q2v, 32);

    f32x4 zero4; zero4[0]=0.f; zero4[1]=0.f; zero4[2]=0.f; zero4[3]=0.f;
    f32x4 acc[NT];
    #pragma unroll
    for (int t = 0; t < NT; ++t) acc[t] = zero4;

    #pragma unroll
    for (int c2 = 0; c2 < NCHUNK; ++c2) {
        __syncthreads();
        {
            const int keyl = tid & (KBLK-1);
            const int half = tid >> 7;
            const int d0 = half*32;
            const float* krow = K + ((size_t)((b*NN + c2*KBLK + keyl)*NH + h))*DD + d0;
            float k2sv = 0.f;
            #pragma unroll
            for (int jj = 0; jj < 8; ++jj) {
                float4 f4 = *(const float4*)(krow + jj*4);
                float fb[4] = {f4.x, f4.y, f4.z, f4.w};
                unsigned short hu[4], lu[4];
                #pragma unroll
                for (int e = 0; e < 4; ++e) {
                    float f = fb[e];
                    k2sv += f*f;
                    hu[e] = f2bf(f);
                    lu[e] = f2bf(f - bf2f(hu[e]));
                }
                int idx = (keyl*DD + d0 + jj*4) ^ ((keyl & 7) << 3);
                *(uint2*)&KhiF[idx] = make_uint2((unsigned)hu[0] | ((unsigned)hu[1] << 16),
                                                 (unsigned)hu[2] | ((unsigned)hu[3] << 16));
                *(uint2*)&KloF[idx] = make_uint2((unsigned)lu[0] | ((unsigned)lu[1] << 16),
                                                 (unsigned)lu[2] | ((unsigned)lu[3] << 16));
            }
            k2p[half][c2*KBLK + keyl] = k2sv;
        }
        __syncthreads();
        #pragma unroll
        for (int tl = 0; tl < TPC; ++tl) {
            const int key = tl*16 + c;
            #pragma unroll
            for (int dc = 0; dc < 2; ++dc) {
                int idx = (key*DD + dc*32 + g*8) ^ ((key & 7) << 3);
                bf16x8 kh = *(const bf16x8*)&KhiF[idx];
                bf16x8 kl = *(const bf16x8*)&KloF[idx];
                acc[c2*TPC+tl] = __builtin_amdgcn_mfma_f32_16x16x32_bf16(qhi[dc], kh, acc[c2*TPC+tl], 0,0,0);
                acc[c2*TPC+tl] = __builtin_amdgcn_mfma_f32_16x16x32_bf16(qlo[dc], kh, acc[c2*TPC+tl], 0,0,0);
                acc[c2*TPC+tl] = __builtin_amdgcn_mfma_f32_16x16x32_bf16(qhi[dc], kl, acc[c2*TPC+tl], 0,0,0);
            }
        }
    }

    float nq2[4];
    #pragma unroll
    for (int r = 0; r < 4; ++r) nq2[r] = -8.f * __shfl(q2v, g*4 + r);

    const float* geoB = GEO + (size_t)b*NN*NN + (size_t)(qb + 4*g)*NN;

    float mx[4] = {-3e38f, -3e38f, -3e38f, -3e38f};
    #pragma unroll
    for (int t = 0; t < NT; ++t) {
        float kk8 = -8.f * (k2p[0][t*16 + c] + k2p[1][t*16 + c]);
        #pragma unroll
        for (int r = 0; r < 4; ++r) {
            float gv = geoB[(size_t)r*NN + t*16 + c];
            float s = fmaf(16.f, acc[t][r], fmaf(8.f, gv, nq2[r] + kk8));
            acc[t][r] = s;
            mx[r] = fmaxf(mx[r], s);
        }
    }
    #pragma unroll
    for (int r = 0; r < 4; ++r) {
        float mv = mx[r];
        mv = fmaxf(mv, __shfl_xor(mv, 1));
        mv = fmaxf(mv, __shfl_xor(mv, 2));
        mv = fmaxf(mv, __shfl_xor(mv, 4));
        mv = fmaxf(mv, __shfl_xor(mv, 8));
        mx[r] = mv;
    }
    float sm[4] = {0.f, 0.f, 0.f, 0.f};
    #pragma unroll
    for (int t = 0; t < NT; ++t) {
        #pragma unroll
        for (int r = 0; r < 4; ++r) {
            float p = __expf(acc[t][r] - mx[r]);
            acc[t][r] = p;
            sm[r] += p;
        }
    }
    #pragma unroll
    for (int r = 0; r < 4; ++r) {
        float sv = sm[r];
        sv += __shfl_xor(sv, 1);
        sv += __shfl_xor(sv, 2);
        sv += __shfl_xor(sv, 4);
        sv += __shfl_xor(sv, 8);
        sm[r] = sv;
    }
    if (c == 0) {
        #pragma unroll
        for (int r = 0; r < 4; ++r) rowinvF[w][4*g + r] = 1.f / sm[r];
    }

    f32x4 oacc[4];
    #pragma unroll
    for (int cb = 0; cb < 4; ++cb) oacc[cb] = zero4;

    #pragma unroll
    for (int c2 = 0; c2 < NCHUNK; ++c2) {
        __syncthreads();
        {
            const int keyl = tid & (KBLK-1);
            const int half = tid >> 7;
            const int d0 = half*32;
            const float* vrow = V + ((size_t)((b*NN + c2*KBLK + keyl)*NH + h))*DD + d0;
            #pragma unroll
            for (int jj = 0; jj < 8; ++jj) {
                float4 f4 = *(const float4*)(vrow + jj*4);
                float fb[4] = {f4.x, f4.y, f4.z, f4.w};
                #pragma unroll
                for (int e = 0; e < 4; ++e) {
                    int d = d0 + jj*4 + e;
                    vTF[(d*KBLK + keyl) ^ ((d & 7) << 3)] = f2bf(fb[e]);
                }
            }
        }
        #pragma unroll
        for (int tl = 0; tl < TPC; ++tl) {
            #pragma unroll
            for (int r = 0; r < 4; ++r) {
                int qloc = 4*g + r;
                PldF[(qloc*KBLK + tl*16 + c) ^ ((qloc & 7) << 3)] = f2bf(acc[c2*TPC+tl][r]);
            }
        }
        __syncthreads();
        #pragma unroll
        for (int kc = 0; kc < 4; ++kc) {
            int kb2 = kc*32 + g*8;
            bf16x8 pf = *(const bf16x8*)&PldF[(c*KBLK + kb2) ^ ((c & 7) << 3)];
            #pragma unroll
            for (int cb = 0; cb < 4; ++cb) {
                int d = cb*16 + c;
                bf16x8 vf = *(const bf16x8*)&vTF[(d*KBLK + kb2) ^ ((d & 7) << 3)];
                oacc[cb] = __builtin_amdgcn_mfma_f32_16x16x32_bf16(vf, pf, oacc[cb], 0,0,0);
            }
        }
    }

    const float inv = rowinvF[w][c];
    float* orow = OUT + ((size_t)((b*NN + qb + c)*NH + h))*DD + 4*g;
    #pragma unroll
    for (int cb = 0; cb < 4; ++cb) {
        float4 ov;
        ov.x = oacc[cb][0] * inv;
        ov.y = oacc[cb][1] * inv;
        ov.z = oacc[cb][2] * inv;
        ov.w = oacc[cb][3] * inv;
        *(float4*)(orow + cb*16) = ov;
    }
}

extern "C" void kernel_launch(void* const* d_in, const int* in_sizes, int n_in,
                              void* d_out, int out_size, void* d_ws, size_t ws_size,
                              hipStream_t stream) {
    const float* q   = (const float*)d_in[0];
    const float* k   = (const float*)d_in[1];
    const float* v   = (const float*)d_in[2];
    const float* geo = (const float*)d_in[3];
    float* out = (float*)d_out;

    const size_t IMG = (size_t)BB*NH*NN*DD*2;   // 8,388,608 B per bf16 image
    const size_t need = 3*IMG + (size_t)BB*NH*NN*4;

    if (ws_size >= need) {
        unsigned short* KhiG = (unsigned short*)d_ws;
        unsigned short* KloG = (unsigned short*)((char*)d_ws + IMG);
        unsigned short* VtG  = (unsigned short*)((char*)d_ws + 2*IMG);
        float*          k2G  = (float*)((char*)d_ws + 3*IMG);
        dim3 pgrid(NCH, NH, BB);
        geo_prep<<<pgrid, 256, 0, stream>>>(k, v, KhiG, KloG, VtG, k2G);
        geo_attn_main<<<dim3(512), 512, 0, stream>>>(q, geo, KhiG, KloG, VtG, k2G, out);
    } else {
        dim3 grid(NN/QBLK, NH, BB);
        geo_attn_fallback<<<grid, 256, 0, stream>>>(q, k, v, geo, out);
    }
}

// Round 9
// 140.204 us; speedup vs baseline: 1.2355x; 1.2355x over previous
//
#include <hip/hip_runtime.h>
#include <hip/hip_bf16.h>

#define BB 16
#define NN 512
#define NH 8
#define DD 64
#define CK 64        // keys per chunk
#define NCH 8        // NN / CK
#define TL 4         // 16-key tiles per chunk
// main kernel
#define MWAVES 8
#define MQBLK 128    // q rows per block (8 waves x 16)
// fallback kernel (round-1)
#define QBLK 64
#define WAVES 4
#define KBLK 128
#define NCHUNK 4
#define NT 32
#define TPC 8

#define C_QK   23.083120654223414f   // 16 * log2(e)
#define C_GEO  11.541560327111707f   // 8 * log2(e)

typedef __attribute__((ext_vector_type(8))) short bf16x8;
typedef __attribute__((ext_vector_type(4))) float f32x4;

__device__ __forceinline__ unsigned short f2bf(float f) {
    unsigned int u = __float_as_uint(f);
    u += 0x7fffu + ((u >> 16) & 1u);     // round-to-nearest-even
    return (unsigned short)(u >> 16);
}
__device__ __forceinline__ float bf2f(unsigned short h) {
    return __uint_as_float(((unsigned int)h) << 16);
}
// packed f32x2 -> bf16x2 (RNE), one instruction
__device__ __forceinline__ unsigned int cvtpk(float a, float b) {
    unsigned int r;
    asm("v_cvt_pk_bf16_f32 %0, %1, %2" : "=v"(r) : "v"(a), "v"(b));
    return r;
}
// 2^x, single v_exp_f32 (no libm slow path)
__device__ __forceinline__ float exp2fast(float x) {
    float r;
    asm("v_exp_f32 %0, %1" : "=v"(r) : "v"(x));
    return r;
}
// async global->LDS, 16B per lane; LDS dest = wave-uniform base + lane*16
__device__ __forceinline__ void gload16(const void* gsrc, void* lds) {
    __builtin_amdgcn_global_load_lds(
        (const __attribute__((address_space(1))) unsigned int*)gsrc,
        (__attribute__((address_space(3))) unsigned int*)lds, 16, 0, 0);
}

// ---------------- prep ----------------
// K image rows PERMUTED so QK^T D-layout slot j=16tl+4g+r holds physical key
// p = 32*(tl>>1) + 8g + 4*(tl&1) + r  ->  each lane's P row is PV-B-frag-ready.
// j(kl) = 16*(((kl&7)>>2) + 2*(kl>>5)) + 4*((kl>>3)&3) + (kl&3)
// V^T image stays physical-key-ordered. k2G stores -8*log2(e)*||k||^2.
__global__ __launch_bounds__(256) void geo_prep(
    const float* __restrict__ K, const float* __restrict__ V,
    unsigned short* __restrict__ KhiG, unsigned short* __restrict__ KloG,
    unsigned short* __restrict__ VtG, float* __restrict__ k2G)
{
    const int c2 = blockIdx.x;   // 0..7 key chunk
    const int h  = blockIdx.y;
    const int b  = blockIdx.z;
    const int bh = b*NH + h;
    const int tid = threadIdx.x;
    const int lane16 = tid & 15;
    const int grp    = tid >> 4;   // 0..15

    __shared__ unsigned short Vl[DD*66];

    const size_t kbase = (size_t)bh*(NN*DD) + (size_t)c2*(CK*DD);
    #pragma unroll
    for (int kk = 0; kk < 4; ++kk) {
        const int kl = kk*16 + grp;
        const float* krow = K + ((size_t)(((b*NN + c2*CK + kl)*NH) + h))*DD + lane16*4;
        const float* vrow = V + ((size_t)(((b*NN + c2*CK + kl)*NH) + h))*DD + lane16*4;
        float4 kf = *(const float4*)krow;
        float4 vf = *(const float4*)vrow;
        float fb[4] = {kf.x, kf.y, kf.z, kf.w};
        float vb[4] = {vf.x, vf.y, vf.z, vf.w};
        unsigned short hu[4], lu[4];
        float k2s = 0.f;
        #pragma unroll
        for (int e = 0; e < 4; ++e) {
            float f = fb[e];
            k2s += f*f;
            hu[e] = f2bf(f);
            lu[e] = f2bf(f - bf2f(hu[e]));
            Vl[(lane16*4 + e)*66 + kl] = f2bf(vb[e]);
        }
        k2s += __shfl_xor(k2s, 1);
        k2s += __shfl_xor(k2s, 2);
        k2s += __shfl_xor(k2s, 4);
        k2s += __shfl_xor(k2s, 8);
        if (lane16 == 0) k2G[bh*NN + c2*CK + kl] = -C_GEO * k2s;   // log2-domain pre-scale
        const int j = 16*(((kl & 7) >> 2) + 2*(kl >> 5)) + 4*((kl >> 3) & 3) + (kl & 3);
        const int pos = (j*DD + lane16*4) ^ ((j & 7) << 3);
        *(uint2*)&KhiG[kbase + pos] = make_uint2((unsigned)hu[0] | ((unsigned)hu[1] << 16),
                                                 (unsigned)hu[2] | ((unsigned)hu[3] << 16));
        *(uint2*)&KloG[kbase + pos] = make_uint2((unsigned)lu[0] | ((unsigned)lu[1] << 16),
                                                 (unsigned)lu[2] | ((unsigned)lu[3] << 16));
    }
    __syncthreads();
    const size_t vbase = ((size_t)bh*NCH + c2)*(DD*CK);
    #pragma unroll
    for (int i = 0; i < 4; ++i) {
        const int gi = tid + 256*i;
        const int d   = gi >> 4;
        const int kl4 = (gi & 15) * 4;
        unsigned short e0 = Vl[d*66 + kl4+0];
        unsigned short e1 = Vl[d*66 + kl4+1];
        unsigned short e2 = Vl[d*66 + kl4+2];
        unsigned short e3 = Vl[d*66 + kl4+3];
        const int pos = (d*CK + kl4) ^ ((d & 7) << 3);
        *(uint2*)&VtG[vbase + pos] = make_uint2((unsigned)e0 | ((unsigned)e1 << 16),
                                                (unsigned)e2 | ((unsigned)e3 << 16));
    }
}

// ---------------- main: swapped QK^T, permuted keys, P in-register,
//   geo prefetched ONE chunk ahead in named registers; cc-loop NOT unrolled
//   (unroll 1 bounds the scheduler horizon -> no cross-chunk load hoisting/spill) ----------------
__global__ __launch_bounds__(512, 4) void geo_attn_main(
    const float* __restrict__ Q, const float* __restrict__ GEO,
    const unsigned short* __restrict__ KhiG, const unsigned short* __restrict__ KloG,
    const unsigned short* __restrict__ VtG, const float* __restrict__ k2G,
    float* __restrict__ OUT)
{
    // XCD-bijective swizzle (512 % 8 == 0): b-major grouping per XCD
    const int bid  = blockIdx.x;
    const int tile = (bid & 7) * 64 + (bid >> 3);
    const int qt = tile & 3;
    const int h  = (tile >> 2) & 7;
    const int b  = tile >> 5;
    const int bh = b*NH + h;
    const int tid = threadIdx.x;
    const int w    = tid >> 6;
    const int lane = tid & 63;
    const int g = lane >> 4;
    const int c = lane & 15;

    __shared__ unsigned short Khi[2][CK*DD];     // 2 x 8KB
    __shared__ unsigned short Klo[2][CK*DD];     // 2 x 8KB
    __shared__ unsigned short vT [2][CK*DD];     // 2 x 8KB
    __shared__ float k2n[NN];                    // 2KB, holds -8*log2e*k2

    k2n[tid] = k2G[(size_t)bh*NN + tid];         // 512 threads == NN

    const int qb = qt*MQBLK + w*16;

    // Q fragments (hi/lo split); q^2 dropped (softmax shift-invariant per row)
    bf16x8 qhi[2], qlo[2];
    {
        const float* qrow = Q + ((size_t)((b*NN + qb + c)*NH + h))*DD;
        #pragma unroll
        for (int dc = 0; dc < 2; ++dc) {
            float buf[8];
            *(float4*)&buf[0] = *(const float4*)(qrow + dc*32 + g*8);
            *(float4*)&buf[4] = *(const float4*)(qrow + dc*32 + g*8 + 4);
            #pragma unroll
            for (int i = 0; i < 8; ++i) {
                float f = buf[i];
                unsigned short hu = f2bf(f);
                qhi[dc][i] = (short)hu;
                qlo[dc][i] = (short)f2bf(f - bf2f(hu));
            }
        }
    }

    f32x4 oacc[4];
    #pragma unroll
    for (int cb = 0; cb < 4; ++cb) { oacc[cb][0]=0.f; oacc[cb][1]=0.f; oacc[cb][2]=0.f; oacc[cb][3]=0.f; }
    float m_run = -3e38f;
    float l_run = 0.f;   // PARTIAL (this replica's 16 keys); reduced once in epilogue

    const char* gKhiB = (const char*)KhiG + (size_t)bh*(NN*DD*2);
    const char* gKloB = (const char*)KloG + (size_t)bh*(NN*DD*2);
    const char* gVtB  = (const char*)VtG  + (size_t)bh*(NN*DD*2);
    const float* geoR = GEO + (size_t)b*NN*NN + (size_t)(qb + c)*NN;   // this lane's q-row
    const int stoff = w*1024 + (lane<<4);

// stage chunk CH2 into buffer BUF (3 async DMAs per wave)
#define STAGE(BUF, CH2) {                                                        \
    const size_t srcoff = (size_t)(CH2)*(CK*DD*2) + stoff;                       \
    gload16(gKhiB + srcoff, (char*)&Khi[BUF][0] + w*1024);                       \
    gload16(gKloB + srcoff, (char*)&Klo[BUF][0] + w*1024);                       \
    gload16(gVtB  + srcoff, (char*)&vT [BUF][0] + w*1024);                       \
}
// geo for chunk CH into 4 named float4s (permuted-slot layout, 4-contiguous)
#define LOAD_GEO(CH, D0, D1, D2, D3) {                                           \
    const float* gb_ = geoR + (CH)*CK + 8*g;                                     \
    D0 = *(const float4*)(gb_);                                                  \
    D1 = *(const float4*)(gb_ + 4);                                              \
    D2 = *(const float4*)(gb_ + 32);                                             \
    D3 = *(const float4*)(gb_ + 36);                                             \
}
// full chunk compute: QK^T (split bf16) -> logits -> online softmax -> PV
#define COMPUTE(CH, CUR, G0, G1, G2, G3) {                                       \
    f32x4 sacc[TL];                                                              \
    _Pragma("unroll")                                                            \
    for (int tl = 0; tl < TL; ++tl) { sacc[tl][0]=0.f; sacc[tl][1]=0.f; sacc[tl][2]=0.f; sacc[tl][3]=0.f; } \
    __builtin_amdgcn_s_setprio(1);                                               \
    _Pragma("unroll")                                                            \
    for (int tl = 0; tl < TL; ++tl) {                                            \
        _Pragma("unroll")                                                        \
        for (int dc = 0; dc < 2; ++dc) {                                         \
            const int idx = ((tl*16 + c)*DD + dc*32 + g*8) ^ ((c & 7) << 3);     \
            bf16x8 kh = *(const bf16x8*)&Khi[CUR][idx];                          \
            bf16x8 kl = *(const bf16x8*)&Klo[CUR][idx];                          \
            sacc[tl] = __builtin_amdgcn_mfma_f32_16x16x32_bf16(kh, qhi[dc], sacc[tl], 0,0,0); \
            sacc[tl] = __builtin_amdgcn_mfma_f32_16x16x32_bf16(kh, qlo[dc], sacc[tl], 0,0,0); \
            sacc[tl] = __builtin_amdgcn_mfma_f32_16x16x32_bf16(kl, qhi[dc], sacc[tl], 0,0,0); \
        }                                                                        \
    }                                                                            \
    __builtin_amdgcn_s_setprio(0);                                               \
    const float4 kn0 = *(const float4*)&k2n[(CH)*CK + 8*g];                      \
    const float4 kn1 = *(const float4*)&k2n[(CH)*CK + 8*g + 4];                  \
    const float4 kn2 = *(const float4*)&k2n[(CH)*CK + 8*g + 32];                 \
    const float4 kn3 = *(const float4*)&k2n[(CH)*CK + 8*g + 36];                 \
    float p[16];                                                                 \
    p[0]  = fmaf(C_QK, sacc[0][0], fmaf(C_GEO, G0.x, kn0.x));                    \
    p[1]  = fmaf(C_QK, sacc[0][1], fmaf(C_GEO, G0.y, kn0.y));                    \
    p[2]  = fmaf(C_QK, sacc[0][2], fmaf(C_GEO, G0.z, kn0.z));                    \
    p[3]  = fmaf(C_QK, sacc[0][3], fmaf(C_GEO, G0.w, kn0.w));                    \
    p[4]  = fmaf(C_QK, sacc[1][0], fmaf(C_GEO, G1.x, kn1.x));                    \
    p[5]  = fmaf(C_QK, sacc[1][1], fmaf(C_GEO, G1.y, kn1.y));                    \
    p[6]  = fmaf(C_QK, sacc[1][2], fmaf(C_GEO, G1.z, kn1.z));                    \
    p[7]  = fmaf(C_QK, sacc[1][3], fmaf(C_GEO, G1.w, kn1.w));                    \
    p[8]  = fmaf(C_QK, sacc[2][0], fmaf(C_GEO, G2.x, kn2.x));                    \
    p[9]  = fmaf(C_QK, sacc[2][1], fmaf(C_GEO, G2.y, kn2.y));                    \
    p[10] = fmaf(C_QK, sacc[2][2], fmaf(C_GEO, G2.z, kn2.z));                    \
    p[11] = fmaf(C_QK, sacc[2][3], fmaf(C_GEO, G2.w, kn2.w));                    \
    p[12] = fmaf(C_QK, sacc[3][0], fmaf(C_GEO, G3.x, kn3.x));                    \
    p[13] = fmaf(C_QK, sacc[3][1], fmaf(C_GEO, G3.y, kn3.y));                    \
    p[14] = fmaf(C_QK, sacc[3][2], fmaf(C_GEO, G3.z, kn3.z));                    \
    p[15] = fmaf(C_QK, sacc[3][3], fmaf(C_GEO, G3.w, kn3.w));                    \
    float mx[8];                                                                 \
    _Pragma("unroll")                                                            \
    for (int i = 0; i < 8; ++i) mx[i] = fmaxf(p[i], p[i+8]);                     \
    _Pragma("unroll")                                                            \
    for (int i = 0; i < 4; ++i) mx[i] = fmaxf(mx[i], mx[i+4]);                   \
    mx[0] = fmaxf(mx[0], mx[2]); mx[1] = fmaxf(mx[1], mx[3]);                    \
    float cmax = fmaxf(mx[0], mx[1]);                                            \
    cmax = fmaxf(cmax, __shfl_xor(cmax, 16));                                    \
    cmax = fmaxf(cmax, __shfl_xor(cmax, 32));                                    \
    const float mnew = fmaxf(m_run, cmax);                                       \
    const float fac = exp2fast(m_run - mnew);                                    \
    m_run = mnew;                                                                \
    _Pragma("unroll")                                                            \
    for (int i = 0; i < 16; ++i) p[i] = exp2fast(p[i] - mnew);                   \
    float sx[8];                                                                 \
    _Pragma("unroll")                                                            \
    for (int i = 0; i < 8; ++i) sx[i] = p[i] + p[i+8];                           \
    _Pragma("unroll")                                                            \
    for (int i = 0; i < 4; ++i) sx[i] = sx[i] + sx[i+4];                         \
    const float cs = (sx[0] + sx[2]) + (sx[1] + sx[3]);                          \
    l_run = fmaf(l_run, fac, cs);  /* partial sum; fac is replica-uniform */     \
    union { unsigned int u[4]; bf16x8 v; } pf0, pf1;                             \
    pf0.u[0] = cvtpk(p[0], p[1]);  pf0.u[1] = cvtpk(p[2],  p[3]);                \
    pf0.u[2] = cvtpk(p[4], p[5]);  pf0.u[3] = cvtpk(p[6],  p[7]);                \
    pf1.u[0] = cvtpk(p[8], p[9]);  pf1.u[1] = cvtpk(p[10], p[11]);               \
    pf1.u[2] = cvtpk(p[12],p[13]); pf1.u[3] = cvtpk(p[14], p[15]);               \
    _Pragma("unroll")                                                            \
    for (int cb = 0; cb < 4; ++cb) {                                             \
        oacc[cb][0] *= fac; oacc[cb][1] *= fac; oacc[cb][2] *= fac; oacc[cb][3] *= fac; \
    }                                                                            \
    __builtin_amdgcn_s_setprio(1);                                               \
    _Pragma("unroll")                                                            \
    for (int kc = 0; kc < 2; ++kc) {                                             \
        bf16x8 pf = kc ? pf1.v : pf0.v;                                          \
        _Pragma("unroll")                                                        \
        for (int cb = 0; cb < 4; ++cb) {                                         \
            const int d = cb*16 + c;                                             \
            bf16x8 vfr = *(const bf16x8*)&vT[CUR][(d*CK + kc*32 + g*8) ^ ((d & 7) << 3)]; \
            oacc[cb] = __builtin_amdgcn_mfma_f32_16x16x32_bf16(vfr, pf, oacc[cb], 0,0,0); \
        }                                                                        \
    }                                                                            \
    __builtin_amdgcn_s_setprio(0);                                               \
}

    float4 gA0, gA1, gA2, gA3;   // geo for current even chunk
    float4 gB0, gB1, gB2, gB3;   // geo for next odd chunk

    // prologue: stage chunk 0, preload its geo
    STAGE(0, 0);
    LOAD_GEO(0, gA0, gA1, gA2, gA3);
    __syncthreads();   // chunk 0 staged + k2n visible

    #pragma unroll 1   // CRITICAL: keep only one even+odd pair in the scheduler's
                       // horizon; full unroll hoisted future geo loads -> scratch spill (R8)
    for (int cc = 0; cc < 4; ++cc) {
        const int ch0 = cc*2;
        // even chunk (buffer 0, geo gA): prefetch odd chunk's K/V + geo
        STAGE(1, ch0 + 1);
        LOAD_GEO(ch0 + 1, gB0, gB1, gB2, gB3);
        COMPUTE(ch0, 0, gA0, gA1, gA2, gA3);
        __syncthreads();
        // odd chunk (buffer 1, geo gB): prefetch next even chunk's K/V + geo
        if (cc < 3) {
            STAGE(0, ch0 + 2);
            LOAD_GEO(ch0 + 2, gA0, gA1, gA2, gA3);
        }
        COMPUTE(ch0 + 1, 1, gB0, gB1, gB2, gB3);
        __syncthreads();
    }

    // epilogue: fold replica partial sums (deferred from the loop), then store
    l_run += __shfl_xor(l_run, 16);
    l_run += __shfl_xor(l_run, 32);
    const float inv = 1.f / l_run;
    float* orow = OUT + ((size_t)((b*NN + qb + c)*NH + h))*DD + 4*g;
    #pragma unroll
    for (int cb = 0; cb < 4; ++cb) {
        float4 ov;
        ov.x = oacc[cb][0] * inv;
        ov.y = oacc[cb][1] * inv;
        ov.z = oacc[cb][2] * inv;
        ov.w = oacc[cb][3] * inv;
        *(float4*)(orow + cb*16) = ov;
    }
#undef STAGE
#undef LOAD_GEO
#undef COMPUTE
}

// ---------------- fallback (round-1 kernel, used if ws too small) ----------------
__global__ __launch_bounds__(256, 2) void geo_attn_fallback(
    const float* __restrict__ Q, const float* __restrict__ K,
    const float* __restrict__ V, const float* __restrict__ GEO,
    float* __restrict__ OUT)
{
    const int qt  = blockIdx.x;
    const int h   = blockIdx.y;
    const int b   = blockIdx.z;
    const int tid = threadIdx.x;
    const int w    = tid >> 6;
    const int lane = tid & 63;
    const int g = lane >> 4;
    const int c = lane & 15;

    __shared__ unsigned short smemA[16384];
    __shared__ float k2p[2][NN];
    __shared__ float rowinvF[WAVES][16];

    unsigned short* KhiF = smemA;
    unsigned short* KloF = smemA + KBLK*DD;
    unsigned short* vTF  = smemA;
    unsigned short* PldF = smemA + DD*KBLK + w*16*KBLK;

    const int qb = qt*QBLK + w*16;

    bf16x8 qhi[2], qlo[2];
    float q2v = 0.f;
    {
        const float* qrow = Q + ((size_t)((b*NN + qb + c)*NH + h))*DD;
        #pragma unroll
        for (int dc = 0; dc < 2; ++dc) {
            float buf[8];
            *(float4*)&buf[0] = *(const float4*)(qrow + dc*32 + g*8);
            *(float4*)&buf[4] = *(const float4*)(qrow + dc*32 + g*8 + 4);
            #pragma unroll
            for (int i = 0; i < 8; ++i) {
                float f = buf[i];
                q2v += f*f;
                unsigned short hu = f2bf(f);
                qhi[dc][i] = (short)hu;
                qlo[dc][i] = (short)f2bf(f - bf2f(hu));
            }
        }
    }
    q2v += __shfl_xor(q2v, 16);
    q2v += __shfl_xor(q2v, 32);

    f32x4 zero4; zero4[0]=0.f; zero4[1]=0.f; zero4[2]=0.f; zero4[3]=0.f;
    f32x4 acc[NT];
    #pragma unroll
    for (int t = 0; t < NT; ++t) acc[t] = zero4;

    #pragma unroll
    for (int c2 = 0; c2 < NCHUNK; ++c2) {
        __syncthreads();
        {
            const int keyl = tid & (KBLK-1);
            const int half = tid >> 7;
            const int d0 = half*32;
            const float* krow = K + ((size_t)((b*NN + c2*KBLK + keyl)*NH + h))*DD + d0;
            float k2sv = 0.f;
            #pragma unroll
            for (int jj = 0; jj < 8; ++jj) {
                float4 f4 = *(const float4*)(krow + jj*4);
                float fb[4] = {f4.x, f4.y, f4.z, f4.w};
                unsigned short hu[4], lu[4];
                #pragma unroll
                for (int e = 0; e < 4; ++e) {
                    float f = fb[e];
                    k2sv += f*f;
                    hu[e] = f2bf(f);
                    lu[e] = f2bf(f - bf2f(hu[e]));
                }
                int idx = (keyl*DD + d0 + jj*4) ^ ((keyl & 7) << 3);
                *(uint2*)&KhiF[idx] = make_uint2((unsigned)hu[0] | ((unsigned)hu[1] << 16),
                                                 (unsigned)hu[2] | ((unsigned)hu[3] << 16));
                *(uint2*)&KloF[idx] = make_uint2((unsigned)lu[0] | ((unsigned)lu[1] << 16),
                                                 (unsigned)lu[2] | ((unsigned)lu[3] << 16));
            }
            k2p[half][c2*KBLK + keyl] = k2sv;
        }
        __syncthreads();
        #pragma unroll
        for (int tl = 0; tl < TPC; ++tl) {
            const int key = tl*16 + c;
            #pragma unroll
            for (int dc = 0; dc < 2; ++dc) {
                int idx = (key*DD + dc*32 + g*8) ^ ((key & 7) << 3);
                bf16x8 kh = *(const bf16x8*)&KhiF[idx];
                bf16x8 kl = *(const bf16x8*)&KloF[idx];
                acc[c2*TPC+tl] = __builtin_amdgcn_mfma_f32_16x16x32_bf16(qhi[dc], kh, acc[c2*TPC+tl], 0,0,0);
                acc[c2*TPC+tl] = __builtin_amdgcn_mfma_f32_16x16x32_bf16(qlo[dc], kh, acc[c2*TPC+tl], 0,0,0);
                acc[c2*TPC+tl] = __builtin_amdgcn_mfma_f32_16x16x32_bf16(qhi[dc], kl, acc[c2*TPC+tl], 0,0,0);
            }
        }
    }

    float nq2[4];
    #pragma unroll
    for (int r = 0; r < 4; ++r) nq2[r] = -8.f * __shfl(q2v, g*4 + r);

    const float* geoB = GEO + (size_t)b*NN*NN + (size_t)(qb + 4*g)*NN;

    float mx[4] = {-3e38f, -3e38f, -3e38f, -3e38f};
    #pragma unroll
    for (int t = 0; t < NT; ++t) {
        float kk8 = -8.f * (k2p[0][t*16 + c] + k2p[1][t*16 + c]);
        #pragma unroll
        for (int r = 0; r < 4; ++r) {
            float gv = geoB[(size_t)r*NN + t*16 + c];
            float s = fmaf(16.f, acc[t][r], fmaf(8.f, gv, nq2[r] + kk8));
            acc[t][r] = s;
            mx[r] = fmaxf(mx[r], s);
        }
    }
    #pragma unroll
    for (int r = 0; r < 4; ++r) {
        float mv = mx[r];
        mv = fmaxf(mv, __shfl_xor(mv, 1));
        mv = fmaxf(mv, __shfl_xor(mv, 2));
        mv = fmaxf(mv, __shfl_xor(mv, 4));
        mv = fmaxf(mv, __shfl_xor(mv, 8));
        mx[r] = mv;
    }
    float sm[4] = {0.f, 0.f, 0.f, 0.f};
    #pragma unroll
    for (int t = 0; t < NT; ++t) {
        #pragma unroll
        for (int r = 0; r < 4; ++r) {
            float p = __expf(acc[t][r] - mx[r]);
            acc[t][r] = p;
            sm[r] += p;
        }
    }
    #pragma unroll
    for (int r = 0; r < 4; ++r) {
        float sv = sm[r];
        sv += __shfl_xor(sv, 1);
        sv += __shfl_xor(sv, 2);
        sv += __shfl_xor(sv, 4);
        sv += __shfl_xor(sv, 8);
        sm[r] = sv;
    }
    if (c == 0) {
        #pragma unroll
        for (int r = 0; r < 4; ++r) rowinvF[w][4*g + r] = 1.f / sm[r];
    }

    f32x4 oacc[4];
    #pragma unroll
    for (int cb = 0; cb < 4; ++cb) oacc[cb] = zero4;

    #pragma unroll
    for (int c2 = 0; c2 < NCHUNK; ++c2) {
        __syncthreads();
        {
            const int keyl = tid & (KBLK-1);
            const int half = tid >> 7;
            const int d0 = half*32;
            const float* vrow = V + ((size_t)((b*NN + c2*KBLK + keyl)*NH + h))*DD + d0;
            #pragma unroll
            for (int jj = 0; jj < 8; ++jj) {
                float4 f4 = *(const float4*)(vrow + jj*4);
                float fb[4] = {f4.x, f4.y, f4.z, f4.w};
                #pragma unroll
                for (int e = 0; e < 4; ++e) {
                    int d = d0 + jj*4 + e;
                    vTF[(d*KBLK + keyl) ^ ((d & 7) << 3)] = f2bf(fb[e]);
                }
            }
        }
        #pragma unroll
        for (int tl = 0; tl < TPC; ++tl) {
            #pragma unroll
            for (int r = 0; r < 4; ++r) {
                int qloc = 4*g + r;
                PldF[(qloc*KBLK + tl*16 + c) ^ ((qloc & 7) << 3)] = f2bf(acc[c2*TPC+tl][r]);
            }
        }
        __syncthreads();
        #pragma unroll
        for (int kc = 0; kc < 4; ++kc) {
            int kb2 = kc*32 + g*8;
            bf16x8 pf = *(const bf16x8*)&PldF[(c*KBLK + kb2) ^ ((c & 7) << 3)];
            #pragma unroll
            for (int cb = 0; cb < 4; ++cb) {
                int d = cb*16 + c;
                bf16x8 vf = *(const bf16x8*)&vTF[(d*KBLK + kb2) ^ ((d & 7) << 3)];
                oacc[cb] = __builtin_amdgcn_mfma_f32_16x16x32_bf16(vf, pf, oacc[cb], 0,0,0);
            }
        }
    }

    const float inv = rowinvF[w][c];
    float* orow = OUT + ((size_t)((b*NN + qb + c)*NH + h))*DD + 4*g;
    #pragma unroll
    for (int cb = 0; cb < 4; ++cb) {
        float4 ov;
        ov.x = oacc[cb][0] * inv;
        ov.y = oacc[cb][1] * inv;
        ov.z = oacc[cb][2] * inv;
        ov.w = oacc[cb][3] * inv;
        *(float4*)(orow + cb*16) = ov;
    }
}

extern "C" void kernel_launch(void* const* d_in, const int* in_sizes, int n_in,
                              void* d_out, int out_size, void* d_ws, size_t ws_size,
                              hipStream_t stream) {
    const float* q   = (const float*)d_in[0];
    const float* k   = (const float*)d_in[1];
    const float* v   = (const float*)d_in[2];
    const float* geo = (const float*)d_in[3];
    float* out = (float*)d_out;

    const size_t IMG = (size_t)BB*NH*NN*DD*2;   // 8,388,608 B per bf16 image
    const size_t need = 3*IMG + (size_t)BB*NH*NN*4;

    if (ws_size >= need) {
        unsigned short* KhiG = (unsigned short*)d_ws;
        unsigned short* KloG = (unsigned short*)((char*)d_ws + IMG);
        unsigned short* VtG  = (unsigned short*)((char*)d_ws + 2*IMG);
        float*          k2G  = (float*)((char*)d_ws + 3*IMG);
        dim3 pgrid(NCH, NH, BB);
        geo_prep<<<pgrid, 256, 0, stream>>>(k, v, KhiG, KloG, VtG, k2G);
        geo_attn_main<<<dim3(512), 512, 0, stream>>>(q, geo, KhiG, KloG, VtG, k2G, out);
    } else {
        dim3 grid(NN/QBLK, NH, BB);
        geo_attn_fallback<<<grid, 256, 0, stream>>>(q, k, v, geo, out);
    }
}

// Round 10
// 127.949 us; speedup vs baseline: 1.3539x; 1.0958x over previous
//
#include <hip/hip_runtime.h>
#include <hip/hip_bf16.h>

#define BB 16
#define NN 512
#define NH 8
#define DD 64
#define CK 64        // keys per chunk
#define NCH 8        // NN / CK
#define TL 4         // 16-key tiles per chunk
// main kernel
#define MWAVES 8
#define MQBLK 128    // q rows per block (8 waves x 16)
// fallback kernel (round-1)
#define QBLK 64
#define WAVES 4
#define KBLK 128
#define NCHUNK 4
#define NT 32
#define TPC 8

#define C_QK   23.083120654223414f   // 16 * log2(e)
#define C_GEO  11.541560327111707f   // 8 * log2(e)

typedef __attribute__((ext_vector_type(8))) short bf16x8;
typedef __attribute__((ext_vector_type(4))) float f32x4;

__device__ __forceinline__ unsigned short f2bf(float f) {
    unsigned int u = __float_as_uint(f);
    u += 0x7fffu + ((u >> 16) & 1u);     // round-to-nearest-even
    return (unsigned short)(u >> 16);
}
__device__ __forceinline__ float bf2f(unsigned short h) {
    return __uint_as_float(((unsigned int)h) << 16);
}
// packed f32x2 -> bf16x2 (RNE), one instruction
__device__ __forceinline__ unsigned int cvtpk(float a, float b) {
    unsigned int r;
    asm("v_cvt_pk_bf16_f32 %0, %1, %2" : "=v"(r) : "v"(a), "v"(b));
    return r;
}
// 2^x, single v_exp_f32 (no libm slow path)
__device__ __forceinline__ float exp2fast(float x) {
    float r;
    asm("v_exp_f32 %0, %1" : "=v"(r) : "v"(x));
    return r;
}
// async global->LDS, 16B per lane; LDS dest = wave-uniform base + lane*16
__device__ __forceinline__ void gload16(const void* gsrc, void* lds) {
    __builtin_amdgcn_global_load_lds(
        (const __attribute__((address_space(1))) unsigned int*)gsrc,
        (__attribute__((address_space(3))) unsigned int*)lds, 16, 0, 0);
}

// ---------------- prep ----------------
// K image rows PERMUTED so QK^T D-layout slot j=16tl+4g+r holds physical key
// p = 32*(tl>>1) + 8g + 4*(tl&1) + r  ->  each lane's P row is PV-B-frag-ready.
// j(kl) = 16*(((kl&7)>>2) + 2*(kl>>5)) + 4*((kl>>3)&3) + (kl&3)
// V^T image stays physical-key-ordered. k2G stores -8*log2(e)*||k||^2.
__global__ __launch_bounds__(256) void geo_prep(
    const float* __restrict__ K, const float* __restrict__ V,
    unsigned short* __restrict__ KhiG, unsigned short* __restrict__ KloG,
    unsigned short* __restrict__ VtG, float* __restrict__ k2G)
{
    const int c2 = blockIdx.x;   // 0..7 key chunk
    const int h  = blockIdx.y;
    const int b  = blockIdx.z;
    const int bh = b*NH + h;
    const int tid = threadIdx.x;
    const int lane16 = tid & 15;
    const int grp    = tid >> 4;   // 0..15

    __shared__ unsigned short Vl[DD*66];

    const size_t kbase = (size_t)bh*(NN*DD) + (size_t)c2*(CK*DD);
    #pragma unroll
    for (int kk = 0; kk < 4; ++kk) {
        const int kl = kk*16 + grp;
        const float* krow = K + ((size_t)(((b*NN + c2*CK + kl)*NH) + h))*DD + lane16*4;
        const float* vrow = V + ((size_t)(((b*NN + c2*CK + kl)*NH) + h))*DD + lane16*4;
        float4 kf = *(const float4*)krow;
        float4 vf = *(const float4*)vrow;
        float fb[4] = {kf.x, kf.y, kf.z, kf.w};
        float vb[4] = {vf.x, vf.y, vf.z, vf.w};
        unsigned short hu[4], lu[4];
        float k2s = 0.f;
        #pragma unroll
        for (int e = 0; e < 4; ++e) {
            float f = fb[e];
            k2s += f*f;
            hu[e] = f2bf(f);
            lu[e] = f2bf(f - bf2f(hu[e]));
            Vl[(lane16*4 + e)*66 + kl] = f2bf(vb[e]);
        }
        k2s += __shfl_xor(k2s, 1);
        k2s += __shfl_xor(k2s, 2);
        k2s += __shfl_xor(k2s, 4);
        k2s += __shfl_xor(k2s, 8);
        if (lane16 == 0) k2G[bh*NN + c2*CK + kl] = -C_GEO * k2s;   // log2-domain pre-scale
        const int j = 16*(((kl & 7) >> 2) + 2*(kl >> 5)) + 4*((kl >> 3) & 3) + (kl & 3);
        const int pos = (j*DD + lane16*4) ^ ((j & 7) << 3);
        *(uint2*)&KhiG[kbase + pos] = make_uint2((unsigned)hu[0] | ((unsigned)hu[1] << 16),
                                                 (unsigned)hu[2] | ((unsigned)hu[3] << 16));
        *(uint2*)&KloG[kbase + pos] = make_uint2((unsigned)lu[0] | ((unsigned)lu[1] << 16),
                                                 (unsigned)lu[2] | ((unsigned)lu[3] << 16));
    }
    __syncthreads();
    const size_t vbase = ((size_t)bh*NCH + c2)*(DD*CK);
    #pragma unroll
    for (int i = 0; i < 4; ++i) {
        const int gi = tid + 256*i;
        const int d   = gi >> 4;
        const int kl4 = (gi & 15) * 4;
        unsigned short e0 = Vl[d*66 + kl4+0];
        unsigned short e1 = Vl[d*66 + kl4+1];
        unsigned short e2 = Vl[d*66 + kl4+2];
        unsigned short e3 = Vl[d*66 + kl4+3];
        const int pos = (d*CK + kl4) ^ ((d & 7) << 3);
        *(uint2*)&VtG[vbase + pos] = make_uint2((unsigned)e0 | ((unsigned)e1 << 16),
                                                (unsigned)e2 | ((unsigned)e3 << 16));
    }
}

// ---------------- main (R7 structure): swapped QK^T, permuted keys, P in-register,
//   geo loaded at top of each chunk (single-buffer, before STAGE so the logit
//   vmcnt wait leaves staging DMAs outstanding). Geo register prefetch across
//   chunks was tried 3x (R5/R8/R9) and always lost to this via pressure/spill. ----------------
__global__ __launch_bounds__(512, 4) void geo_attn_main(
    const float* __restrict__ Q, const float* __restrict__ GEO,
    const unsigned short* __restrict__ KhiG, const unsigned short* __restrict__ KloG,
    const unsigned short* __restrict__ VtG, const float* __restrict__ k2G,
    float* __restrict__ OUT)
{
    // XCD-bijective swizzle (512 % 8 == 0): b-major grouping per XCD
    const int bid  = blockIdx.x;
    const int tile = (bid & 7) * 64 + (bid >> 3);
    const int qt = tile & 3;
    const int h  = (tile >> 2) & 7;
    const int b  = tile >> 5;
    const int bh = b*NH + h;
    const int tid = threadIdx.x;
    const int w    = tid >> 6;
    const int lane = tid & 63;
    const int g = lane >> 4;
    const int c = lane & 15;

    __shared__ unsigned short Khi[2][CK*DD];     // 2 x 8KB
    __shared__ unsigned short Klo[2][CK*DD];     // 2 x 8KB
    __shared__ unsigned short vT [2][CK*DD];     // 2 x 8KB
    __shared__ float k2n[NN];                    // 2KB, holds -8*log2e*k2

    k2n[tid] = k2G[(size_t)bh*NN + tid];         // 512 threads == NN

    const int qb = qt*MQBLK + w*16;

    // Q fragments (hi/lo split); q^2 dropped (softmax shift-invariant per row)
    bf16x8 qhi[2], qlo[2];
    {
        const float* qrow = Q + ((size_t)((b*NN + qb + c)*NH + h))*DD;
        #pragma unroll
        for (int dc = 0; dc < 2; ++dc) {
            float buf[8];
            *(float4*)&buf[0] = *(const float4*)(qrow + dc*32 + g*8);
            *(float4*)&buf[4] = *(const float4*)(qrow + dc*32 + g*8 + 4);
            #pragma unroll
            for (int i = 0; i < 8; ++i) {
                float f = buf[i];
                unsigned short hu = f2bf(f);
                qhi[dc][i] = (short)hu;
                qlo[dc][i] = (short)f2bf(f - bf2f(hu));
            }
        }
    }

    f32x4 oacc[4];
    #pragma unroll
    for (int cb = 0; cb < 4; ++cb) { oacc[cb][0]=0.f; oacc[cb][1]=0.f; oacc[cb][2]=0.f; oacc[cb][3]=0.f; }
    float m_run = -3e38f;
    float l_run = 0.f;   // PARTIAL (this replica's 16 keys); folded once in epilogue

    const char* gKhiB = (const char*)KhiG + (size_t)bh*(NN*DD*2);
    const char* gKloB = (const char*)KloG + (size_t)bh*(NN*DD*2);
    const char* gVtB  = (const char*)VtG  + (size_t)bh*(NN*DD*2);
    const float* geoR = GEO + (size_t)b*NN*NN + (size_t)(qb + c)*NN;   // this lane's q-row
    const int stoff = w*1024 + (lane<<4);

    // stage chunk 0
    gload16(gKhiB + stoff, (char*)&Khi[0][0] + w*1024);
    gload16(gKloB + stoff, (char*)&Klo[0][0] + w*1024);
    gload16(gVtB  + stoff, (char*)&vT [0][0] + w*1024);
    __syncthreads();   // chunk 0 staged + k2n visible

    for (int ch = 0; ch < NCH; ++ch) {
        const int cur = ch & 1;

        // geo float4 loads FIRST (in-order vmcnt: logit wait won't drain stage DMAs)
        const float* gbase = geoR + ch*CK + 8*g;
        const float4 gq0 = *(const float4*)(gbase);
        const float4 gq1 = *(const float4*)(gbase + 4);
        const float4 gq2 = *(const float4*)(gbase + 32);
        const float4 gq3 = *(const float4*)(gbase + 36);

        if (ch + 1 < NCH) {   // prefetch next chunk into other buffer
            const size_t srcoff = (size_t)(ch+1)*(CK*DD*2) + stoff;
            gload16(gKhiB + srcoff, (char*)&Khi[cur^1][0] + w*1024);
            gload16(gKloB + srcoff, (char*)&Klo[cur^1][0] + w*1024);
            gload16(gVtB  + srcoff, (char*)&vT [cur^1][0] + w*1024);
        }

        // QK^T swapped (A=K, B=Q): sacc[tl][r] = S[q=qb+c][key 32*(tl>>1)+8g+4*(tl&1)+r]
        f32x4 sacc[TL];
        #pragma unroll
        for (int tl = 0; tl < TL; ++tl) { sacc[tl][0]=0.f; sacc[tl][1]=0.f; sacc[tl][2]=0.f; sacc[tl][3]=0.f; }
        __builtin_amdgcn_s_setprio(1);
        #pragma unroll
        for (int tl = 0; tl < TL; ++tl) {
            #pragma unroll
            for (int dc = 0; dc < 2; ++dc) {
                const int idx = ((tl*16 + c)*DD + dc*32 + g*8) ^ ((c & 7) << 3);
                bf16x8 kh = *(const bf16x8*)&Khi[cur][idx];
                bf16x8 kl = *(const bf16x8*)&Klo[cur][idx];
                sacc[tl] = __builtin_amdgcn_mfma_f32_16x16x32_bf16(kh, qhi[dc], sacc[tl], 0,0,0);
                sacc[tl] = __builtin_amdgcn_mfma_f32_16x16x32_bf16(kh, qlo[dc], sacc[tl], 0,0,0);
                sacc[tl] = __builtin_amdgcn_mfma_f32_16x16x32_bf16(kl, qhi[dc], sacc[tl], 0,0,0);
            }
        }
        __builtin_amdgcn_s_setprio(0);

        // k2 terms from LDS (broadcast within c-group, conflict-free)
        const float4 kn0 = *(const float4*)&k2n[ch*CK + 8*g];
        const float4 kn1 = *(const float4*)&k2n[ch*CK + 8*g + 4];
        const float4 kn2 = *(const float4*)&k2n[ch*CK + 8*g + 32];
        const float4 kn3 = *(const float4*)&k2n[ch*CK + 8*g + 36];

        // logits in log2 domain: p = C_QK*qk + C_GEO*geo + k2n
        float p[16];
        p[0]  = fmaf(C_QK, sacc[0][0], fmaf(C_GEO, gq0.x, kn0.x));
        p[1]  = fmaf(C_QK, sacc[0][1], fmaf(C_GEO, gq0.y, kn0.y));
        p[2]  = fmaf(C_QK, sacc[0][2], fmaf(C_GEO, gq0.z, kn0.z));
        p[3]  = fmaf(C_QK, sacc[0][3], fmaf(C_GEO, gq0.w, kn0.w));
        p[4]  = fmaf(C_QK, sacc[1][0], fmaf(C_GEO, gq1.x, kn1.x));
        p[5]  = fmaf(C_QK, sacc[1][1], fmaf(C_GEO, gq1.y, kn1.y));
        p[6]  = fmaf(C_QK, sacc[1][2], fmaf(C_GEO, gq1.z, kn1.z));
        p[7]  = fmaf(C_QK, sacc[1][3], fmaf(C_GEO, gq1.w, kn1.w));
        p[8]  = fmaf(C_QK, sacc[2][0], fmaf(C_GEO, gq2.x, kn2.x));
        p[9]  = fmaf(C_QK, sacc[2][1], fmaf(C_GEO, gq2.y, kn2.y));
        p[10] = fmaf(C_QK, sacc[2][2], fmaf(C_GEO, gq2.z, kn2.z));
        p[11] = fmaf(C_QK, sacc[2][3], fmaf(C_GEO, gq2.w, kn2.w));
        p[12] = fmaf(C_QK, sacc[3][0], fmaf(C_GEO, gq3.x, kn3.x));
        p[13] = fmaf(C_QK, sacc[3][1], fmaf(C_GEO, gq3.y, kn3.y));
        p[14] = fmaf(C_QK, sacc[3][2], fmaf(C_GEO, gq3.z, kn3.z));
        p[15] = fmaf(C_QK, sacc[3][3], fmaf(C_GEO, gq3.w, kn3.w));

        // tree max (depth 4) + 2 cross-replica shuffles (max must be exact per row)
        float mx[8];
        #pragma unroll
        for (int i = 0; i < 8; ++i) mx[i] = fmaxf(p[i], p[i+8]);
        #pragma unroll
        for (int i = 0; i < 4; ++i) mx[i] = fmaxf(mx[i], mx[i+4]);
        mx[0] = fmaxf(mx[0], mx[2]); mx[1] = fmaxf(mx[1], mx[3]);
        float cmax = fmaxf(mx[0], mx[1]);
        cmax = fmaxf(cmax, __shfl_xor(cmax, 16));
        cmax = fmaxf(cmax, __shfl_xor(cmax, 32));
        const float mnew = fmaxf(m_run, cmax);
        const float fac = exp2fast(m_run - mnew);
        m_run = mnew;
        #pragma unroll
        for (int i = 0; i < 16; ++i) p[i] = exp2fast(p[i] - mnew);
        float sx[8];
        #pragma unroll
        for (int i = 0; i < 8; ++i) sx[i] = p[i] + p[i+8];
        #pragma unroll
        for (int i = 0; i < 4; ++i) sx[i] = sx[i] + sx[i+4];
        const float cs = (sx[0] + sx[2]) + (sx[1] + sx[3]);
        // l_run stays a per-replica partial: fac is replica-uniform (cmax fully
        // reduced), so the cross-replica fold commutes to the epilogue.
        l_run = fmaf(l_run, fac, cs);

        // P -> PV B-frags IN REGISTER (permuted keys: p[0..7]=keys g*8+i, p[8..15]=32+g*8+i)
        union { unsigned int u[4]; bf16x8 v; } pf0, pf1;
        pf0.u[0] = cvtpk(p[0], p[1]);  pf0.u[1] = cvtpk(p[2],  p[3]);
        pf0.u[2] = cvtpk(p[4], p[5]);  pf0.u[3] = cvtpk(p[6],  p[7]);
        pf1.u[0] = cvtpk(p[8], p[9]);  pf1.u[1] = cvtpk(p[10], p[11]);
        pf1.u[2] = cvtpk(p[12],p[13]); pf1.u[3] = cvtpk(p[14], p[15]);

        // PV accumulate (out^T = V^T * P^T); fac lane-local
        #pragma unroll
        for (int cb = 0; cb < 4; ++cb) {
            oacc[cb][0] *= fac; oacc[cb][1] *= fac; oacc[cb][2] *= fac; oacc[cb][3] *= fac;
        }
        __builtin_amdgcn_s_setprio(1);
        #pragma unroll
        for (int kc = 0; kc < 2; ++kc) {
            bf16x8 pf = kc ? pf1.v : pf0.v;
            #pragma unroll
            for (int cb = 0; cb < 4; ++cb) {
                const int d = cb*16 + c;
                bf16x8 vfr = *(const bf16x8*)&vT[cur][(d*CK + kc*32 + g*8) ^ ((d & 7) << 3)];
                oacc[cb] = __builtin_amdgcn_mfma_f32_16x16x32_bf16(vfr, pf, oacc[cb], 0,0,0);
            }
        }
        __builtin_amdgcn_s_setprio(0);
        __syncthreads();   // all waves done with buf[cur]; prefetch DMA drained
    }

    // epilogue: fold replica partial sums once, then store
    l_run += __shfl_xor(l_run, 16);
    l_run += __shfl_xor(l_run, 32);
    const float inv = 1.f / l_run;
    float* orow = OUT + ((size_t)((b*NN + qb + c)*NH + h))*DD + 4*g;
    #pragma unroll
    for (int cb = 0; cb < 4; ++cb) {
        float4 ov;
        ov.x = oacc[cb][0] * inv;
        ov.y = oacc[cb][1] * inv;
        ov.z = oacc[cb][2] * inv;
        ov.w = oacc[cb][3] * inv;
        *(float4*)(orow + cb*16) = ov;
    }
}

// ---------------- fallback (round-1 kernel, used if ws too small) ----------------
__global__ __launch_bounds__(256, 2) void geo_attn_fallback(
    const float* __restrict__ Q, const float* __restrict__ K,
    const float* __restrict__ V, const float* __restrict__ GEO,
    float* __restrict__ OUT)
{
    const int qt  = blockIdx.x;
    const int h   = blockIdx.y;
    const int b   = blockIdx.z;
    const int tid = threadIdx.x;
    const int w    = tid >> 6;
    const int lane = tid & 63;
    const int g = lane >> 4;
    const int c = lane & 15;

    __shared__ unsigned short smemA[16384];
    __shared__ float k2p[2][NN];
    __shared__ float rowinvF[WAVES][16];

    unsigned short* KhiF = smemA;
    unsigned short* KloF = smemA + KBLK*DD;
    unsigned short* vTF  = smemA;
    unsigned short* PldF = smemA + DD*KBLK + w*16*KBLK;

    const int qb = qt*QBLK + w*16;

    bf16x8 qhi[2], qlo[2];
    float q2v = 0.f;
    {
        const float* qrow = Q + ((size_t)((b*NN + qb + c)*NH + h))*DD;
        #pragma unroll
        for (int dc = 0; dc < 2; ++dc) {
            float buf[8];
            *(float4*)&buf[0] = *(const float4*)(qrow + dc*32 + g*8);
            *(float4*)&buf[4] = *(const float4*)(qrow + dc*32 + g*8 + 4);
            #pragma unroll
            for (int i = 0; i < 8; ++i) {
                float f = buf[i];
                q2v += f*f;
                unsigned short hu = f2bf(f);
                qhi[dc][i] = (short)hu;
                qlo[dc][i] = (short)f2bf(f - bf2f(hu));
            }
        }
    }
    q2v += __shfl_xor(q2v, 16);
    q2v += __shfl_xor(q2v, 32);

    f32x4 zero4; zero4[0]=0.f; zero4[1]=0.f; zero4[2]=0.f; zero4[3]=0.f;
    f32x4 acc[NT];
    #pragma unroll
    for (int t = 0; t < NT; ++t) acc[t] = zero4;

    #pragma unroll
    for (int c2 = 0; c2 < NCHUNK; ++c2) {
        __syncthreads();
        {
            const int keyl = tid & (KBLK-1);
            const int half = tid >> 7;
            const int d0 = half*32;
            const float* krow = K + ((size_t)((b*NN + c2*KBLK + keyl)*NH + h))*DD + d0;
            float k2sv = 0.f;
            #pragma unroll
            for (int jj = 0; jj < 8; ++jj) {
                float4 f4 = *(const float4*)(krow + jj*4);
                float fb[4] = {f4.x, f4.y, f4.z, f4.w};
                unsigned short hu[4], lu[4];
                #pragma unroll
                for (int e = 0; e < 4; ++e) {
                    float f = fb[e];
                    k2sv += f*f;
                    hu[e] = f2bf(f);
                    lu[e] = f2bf(f - bf2f(hu[e]));
                }
                int idx = (keyl*DD + d0 + jj*4) ^ ((keyl & 7) << 3);
                *(uint2*)&KhiF[idx] = make_uint2((unsigned)hu[0] | ((unsigned)hu[1] << 16),
                                                 (unsigned)hu[2] | ((unsigned)hu[3] << 16));
                *(uint2*)&KloF[idx] = make_uint2((unsigned)lu[0] | ((unsigned)lu[1] << 16),
                                                 (unsigned)lu[2] | ((unsigned)lu[3] << 16));
            }
            k2p[half][c2*KBLK + keyl] = k2sv;
        }
        __syncthreads();
        #pragma unroll
        for (int tl = 0; tl < TPC; ++tl) {
            const int key = tl*16 + c;
            #pragma unroll
            for (int dc = 0; dc < 2; ++dc) {
                int idx = (key*DD + dc*32 + g*8) ^ ((key & 7) << 3);
                bf16x8 kh = *(const bf16x8*)&KhiF[idx];
                bf16x8 kl = *(const bf16x8*)&KloF[idx];
                acc[c2*TPC+tl] = __builtin_amdgcn_mfma_f32_16x16x32_bf16(qhi[dc], kh, acc[c2*TPC+tl], 0,0,0);
                acc[c2*TPC+tl] = __builtin_amdgcn_mfma_f32_16x16x32_bf16(qlo[dc], kh, acc[c2*TPC+tl], 0,0,0);
                acc[c2*TPC+tl] = __builtin_amdgcn_mfma_f32_16x16x32_bf16(qhi[dc], kl, acc[c2*TPC+tl], 0,0,0);
            }
        }
    }

    float nq2[4];
    #pragma unroll
    for (int r = 0; r < 4; ++r) nq2[r] = -8.f * __shfl(q2v, g*4 + r);

    const float* geoB = GEO + (size_t)b*NN*NN + (size_t)(qb + 4*g)*NN;

    float mx[4] = {-3e38f, -3e38f, -3e38f, -3e38f};
    #pragma unroll
    for (int t = 0; t < NT; ++t) {
        float kk8 = -8.f * (k2p[0][t*16 + c] + k2p[1][t*16 + c]);
        #pragma unroll
        for (int r = 0; r < 4; ++r) {
            float gv = geoB[(size_t)r*NN + t*16 + c];
            float s = fmaf(16.f, acc[t][r], fmaf(8.f, gv, nq2[r] + kk8));
            acc[t][r] = s;
            mx[r] = fmaxf(mx[r], s);
        }
    }
    #pragma unroll
    for (int r = 0; r < 4; ++r) {
        float mv = mx[r];
        mv = fmaxf(mv, __shfl_xor(mv, 1));
        mv = fmaxf(mv, __shfl_xor(mv, 2));
        mv = fmaxf(mv, __shfl_xor(mv, 4));
        mv = fmaxf(mv, __shfl_xor(mv, 8));
        mx[r] = mv;
    }
    float sm[4] = {0.f, 0.f, 0.f, 0.f};
    #pragma unroll
    for (int t = 0; t < NT; ++t) {
        #pragma unroll
        for (int r = 0; r < 4; ++r) {
            float p = __expf(acc[t][r] - mx[r]);
            acc[t][r] = p;
            sm[r] += p;
        }
    }
    #pragma unroll
    for (int r = 0; r < 4; ++r) {
        float sv = sm[r];
        sv += __shfl_xor(sv, 1);
        sv += __shfl_xor(sv, 2);
        sv += __shfl_xor(sv, 4);
        sv += __shfl_xor(sv, 8);
        sm[r] = sv;
    }
    if (c == 0) {
        #pragma unroll
        for (int r = 0; r < 4; ++r) rowinvF[w][4*g + r] = 1.f / sm[r];
    }

    f32x4 oacc[4];
    #pragma unroll
    for (int cb = 0; cb < 4; ++cb) oacc[cb] = zero4;

    #pragma unroll
    for (int c2 = 0; c2 < NCHUNK; ++c2) {
        __syncthreads();
        {
            const int keyl = tid & (KBLK-1);
            const int half = tid >> 7;
            const int d0 = half*32;
            const float* vrow = V + ((size_t)((b*NN + c2*KBLK + keyl)*NH + h))*DD + d0;
            #pragma unroll
            for (int jj = 0; jj < 8; ++jj) {
                float4 f4 = *(const float4*)(vrow + jj*4);
                float fb[4] = {f4.x, f4.y, f4.z, f4.w};
                #pragma unroll
                for (int e = 0; e < 4; ++e) {
                    int d = d0 + jj*4 + e;
                    vTF[(d*KBLK + keyl) ^ ((d & 7) << 3)] = f2bf(fb[e]);
                }
            }
        }
        #pragma unroll
        for (int tl = 0; tl < TPC; ++tl) {
            #pragma unroll
            for (int r = 0; r < 4; ++r) {
                int qloc = 4*g + r;
                PldF[(qloc*KBLK + tl*16 + c) ^ ((qloc & 7) << 3)] = f2bf(acc[c2*TPC+tl][r]);
            }
        }
        __syncthreads();
        #pragma unroll
        for (int kc = 0; kc < 4; ++kc) {
            int kb2 = kc*32 + g*8;
            bf16x8 pf = *(const bf16x8*)&PldF[(c*KBLK + kb2) ^ ((c & 7) << 3)];
            #pragma unroll
            for (int cb = 0; cb < 4; ++cb) {
                int d = cb*16 + c;
                bf16x8 vf = *(const bf16x8*)&vTF[(d*KBLK + kb2) ^ ((d & 7) << 3)];
                oacc[cb] = __builtin_amdgcn_mfma_f32_16x16x32_bf16(vf, pf, oacc[cb], 0,0,0);
            }
        }
    }

    const float inv = rowinvF[w][c];
    float* orow = OUT + ((size_t)((b*NN + qb + c)*NH + h))*DD + 4*g;
    #pragma unroll
    for (int cb = 0; cb < 4; ++cb) {
        float4 ov;
        ov.x = oacc[cb][0] * inv;
        ov.y = oacc[cb][1] * inv;
        ov.z = oacc[cb][2] * inv;
        ov.w = oacc[cb][3] * inv;
        *(float4*)(orow + cb*16) = ov;
    }
}

extern "C" void kernel_launch(void* const* d_in, const int* in_sizes, int n_in,
                              void* d_out, int out_size, void* d_ws, size_t ws_size,
                              hipStream_t stream) {
    const float* q   = (const float*)d_in[0];
    const float* k   = (const float*)d_in[1];
    const float* v   = (const float*)d_in[2];
    const float* geo = (const float*)d_in[3];
    float* out = (float*)d_out;

    const size_t IMG = (size_t)BB*NH*NN*DD*2;   // 8,388,608 B per bf16 image
    const size_t need = 3*IMG + (size_t)BB*NH*NN*4;

    if (ws_size >= need) {
        unsigned short* KhiG = (unsigned short*)d_ws;
        unsigned short* KloG = (unsigned short*)((char*)d_ws + IMG);
        unsigned short* VtG  = (unsigned short*)((char*)d_ws + 2*IMG);
        float*          k2G  = (float*)((char*)d_ws + 3*IMG);
        dim3 pgrid(NCH, NH, BB);
        geo_prep<<<pgrid, 256, 0, stream>>>(k, v, KhiG, KloG, VtG, k2G);
        geo_attn_main<<<dim3(512), 512, 0, stream>>>(q, geo, KhiG, KloG, VtG, k2G, out);
    } else {
        dim3 grid(NN/QBLK, NH, BB);
        geo_attn_fallback<<<grid, 256, 0, stream>>>(q, k, v, geo, out);
    }
}